// Round 5
// baseline (293.017 us; speedup 1.0000x reference)
//
#include <hip/hip_runtime.h>
#include <hip/hip_fp16.h>
#include <math.h>

#define BATCH 8
#define N 2048
#define D 128
#define ST 4000

#define TJ 64        // j-tile per K-step
#define IT 16        // i-rows per block (one i-tile, shared by 4 k-quarter waves)
#define KQ 4         // K-quarters = waves per block
#define TPW 8        // tiles per wave = N/TJ/KQ

typedef short bf16x8 __attribute__((ext_vector_type(8)));
typedef float f32x4  __attribute__((ext_vector_type(4)));
typedef unsigned short u16x4 __attribute__((ext_vector_type(4)));

__device__ __forceinline__ unsigned short f2bf(float f) {
    union { float f; unsigned u; } v; v.f = f;
    const unsigned r = v.u + 0x7FFFu + ((v.u >> 16) & 1u);   // RNE
    return (unsigned short)(r >> 16);
}

// ---------------------------------------------------------------------------
// Counting sort per batch (values < 4000). Also exports the histogram as
// cntT[c][b] (u16) for the pack kernel's denominator precompute.
// ---------------------------------------------------------------------------
__global__ __launch_bounds__(1024) void sort_kernel(
    const int* __restrict__ stk_ten,
    int* __restrict__ sval,
    int* __restrict__ spos,
    unsigned short* __restrict__ cntT)
{
    __shared__ int hist[4000];
    __shared__ int base[4000];
    __shared__ int wsum[16];
    const int b = blockIdx.x, t = threadIdx.x;
    const int lane = t & 63, wv = t >> 6;
    const int* idxb = stk_ten + b * N;

    for (int j = t; j < 4000; j += 1024) hist[j] = 0;
    __syncthreads();
    const int v0 = idxb[t], v1 = idxb[t + 1024];
    atomicAdd(&hist[v0], 1);
    atomicAdd(&hist[v1], 1);
    __syncthreads();

    // export counts for pack's denominator GEMV
    for (int j = t; j < 4000; j += 1024) cntT[(size_t)j * 8 + b] = (unsigned short)hist[j];

    // scan: thread owns bins 4t..4t+3
    int h[4], c[4], run = 0;
    #pragma unroll
    for (int i = 0; i < 4; ++i) {
        const int bi = 4 * t + i;
        h[i] = (bi < 4000) ? hist[bi] : 0;
        run += h[i];
        c[i] = run;
    }
    const int tsum = run;
    int incl = tsum;
    #pragma unroll
    for (int d = 1; d < 64; d <<= 1) {
        const int tmp = __shfl_up(incl, d, 64);
        if (lane >= d) incl += tmp;
    }
    if (lane == 63) wsum[wv] = incl;
    __syncthreads();
    if (t < 16) {
        const int v = wsum[t];
        int iv = v;
        #pragma unroll
        for (int d = 1; d < 16; d <<= 1) {
            const int tmp = __shfl_up(iv, d, 64);
            if (lane >= d) iv += tmp;
        }
        wsum[t] = iv - v;               // exclusive across waves
    }
    __syncthreads();
    const int ex = incl - tsum + wsum[wv];
    #pragma unroll
    for (int i = 0; i < 4; ++i) {
        const int bi = 4 * t + i;
        if (bi < 4000) base[bi] = ex + c[i] - h[i];
    }
    __syncthreads();
    for (int j = t; j < 4000; j += 1024) hist[j] = 0;
    __syncthreads();
    {
        const int p0 = base[v0] + atomicAdd(&hist[v0], 1);
        sval[b * N + p0] = v0; spos[b * N + p0] = t;
        const int p1 = base[v1] + atomicAdd(&hist[v1], 1);
        sval[b * N + p1] = v1; spos[b * N + p1] = t + 1024;
    }
}

// ---------------------------------------------------------------------------
// Pack kernel (one block per row r):
//   P2[r][c] = bf16(M[r][c] * exp|W[r][c]|)          (u16 -> 32 MB, was 64)
//   Lb[b][r] = sum_c cnt_b[c]*exp|W[r][c]| - exp|W[r][r]| + 1
// The denominator leaves the latency-critical fused loop entirely: the
// j-multiset is batch-global, so l[i] is a count-weighted row sum.
// ---------------------------------------------------------------------------
__global__ __launch_bounds__(256) void pack_kernel(
    const float* __restrict__ M, const float* __restrict__ W,
    const unsigned short* __restrict__ cntT,    // [ST][8]
    unsigned short* __restrict__ P2,            // [ST][ST]
    float* __restrict__ Lb)                     // [BATCH][ST]
{
    __shared__ float redL[4][8];
    __shared__ float ediag_s;
    const int r = blockIdx.x;
    const int t = threadIdx.x;
    const int lane = t & 63, wv = t >> 6;
    const size_t rowo = (size_t)r * ST;

    float acc8[8];
    #pragma unroll
    for (int b = 0; b < 8; ++b) acc8[b] = 0.0f;

    for (int it = 0; it < 4; ++it) {
        const int c4 = (t + 256 * it) * 4;
        if (c4 < ST) {
            const f32x4 m4 = __builtin_nontemporal_load((const f32x4*)(M + rowo + c4));
            const f32x4 w4 = __builtin_nontemporal_load((const f32x4*)(W + rowo + c4));
            u16x4 o;
            #pragma unroll
            for (int k = 0; k < 4; ++k) {
                const float e = __expf(fabsf(w4[k]));
                o[k] = f2bf(m4[k] * e);
                if (c4 + k == r) ediag_s = e;
                const uint4 cv = *(const uint4*)(cntT + (size_t)(c4 + k) * 8);
                acc8[0] += (float)(cv.x & 0xFFFFu) * e;
                acc8[1] += (float)(cv.x >> 16)     * e;
                acc8[2] += (float)(cv.y & 0xFFFFu) * e;
                acc8[3] += (float)(cv.y >> 16)     * e;
                acc8[4] += (float)(cv.z & 0xFFFFu) * e;
                acc8[5] += (float)(cv.z >> 16)     * e;
                acc8[6] += (float)(cv.w & 0xFFFFu) * e;
                acc8[7] += (float)(cv.w >> 16)     * e;
            }
            *(u16x4*)(P2 + rowo + c4) = o;
        }
    }

    #pragma unroll
    for (int b = 0; b < 8; ++b) {
        float v = acc8[b];
        #pragma unroll
        for (int d = 1; d < 64; d <<= 1) v += __shfl_xor(v, d, 64);
        if (lane == 0) redL[wv][b] = v;
    }
    __syncthreads();
    if (t < 8) {
        const float s = redL[0][t] + redL[1][t] + redL[2][t] + redL[3][t];
        Lb[(size_t)t * ST + r] = s - ediag_s + 1.0f;
    }
}

// ---------------------------------------------------------------------------
// xT[b][d][j_sorted] = bf16(x[b][spos[j]][d]).  4 MB, L2-resident B operand.
// ---------------------------------------------------------------------------
__global__ __launch_bounds__(256) void xt_kernel(
    const float* __restrict__ x,
    const int* __restrict__ spos,
    unsigned short* __restrict__ xT)
{
    __shared__ float xs[TJ][129];
    __shared__ int sp_s[TJ];
    const int t  = threadIdx.x;
    const int b  = blockIdx.x >> 5;
    const int jt = blockIdx.x & 31;
    const int j0 = jt * TJ;
    if (t < TJ) sp_s[t] = spos[b * N + j0 + t];
    __syncthreads();
    const int tx = t & 31, ty = t >> 5;
    const float* xb = x + (size_t)b * N * D;
    #pragma unroll
    for (int p = 0; p < 8; ++p) {
        const int r = ty + 8 * p;
        const float* src = xb + (size_t)sp_s[r] * D;
        #pragma unroll
        for (int i = 0; i < 4; ++i)
            xs[r][tx + 32 * i] = src[tx + 32 * i];
    }
    __syncthreads();
    const int jp = t & 31, dd0 = t >> 5;
    unsigned short* xTb = xT + (size_t)b * D * N;
    #pragma unroll
    for (int q = 0; q < 16; ++q) {
        const int dd = dd0 + 8 * q;
        const unsigned lo = f2bf(xs[2 * jp][dd]);
        const unsigned hi = f2bf(xs[2 * jp + 1][dd]);
        *(unsigned*)(xTb + (size_t)dd * N + j0 + 2 * jp) = (hi << 16) | lo;
    }
}

// ---------------------------------------------------------------------------
// Fused kernel = round-0 pipeline (proven-fast, 87.5us), slimmed:
//  - u16 gathers from P2 (half the gather traffic of packed u32)
//  - NO denominator work in the loop (Lb precomputed in pack): no l_part
//    VGPRs, no e-unpack, no epilogue butterfly. Coef loop = select + store.
//  - NO occupancy attribute: rounds 1/2/4 proved every cap (128-unified or
//    waves_per_eu) makes the allocator squeeze to 52-64 arch VGPRs and
//    serialize the 16-wide gather pipeline. The slimmer loop should land
//    naturally at ~110-125 unified -> 4 waves/EU with full ILP.
// Verification signal: VGPR_Count ~72-96 (NOT <=64), Occupancy ~50%.
// ---------------------------------------------------------------------------
__global__ __launch_bounds__(256) void fused_kernel(
    const unsigned short* __restrict__ xT,
    const int* __restrict__ stk_ten,
    const unsigned short* __restrict__ P2,
    const int* __restrict__ sval,
    const int* __restrict__ spos,
    const float* __restrict__ Lb,
    float* __restrict__ out)
{
    __shared__ __align__(16) unsigned short cs[KQ][IT * 72]; // 9216 B, per-wave
    __shared__ float accs[IT][132];                          // 8448 B
    __shared__ int ri_s[IT];

    const int t    = threadIdx.x;
    const int lane = t & 63;
    const int w    = t >> 6;
    const int wg   = (blockIdx.x & 7) * 128 + (blockIdx.x >> 3);  // batch->XCD
    const int b    = wg >> 7;                    // 128 i-tiles per batch
    const int i0   = (wg & 127) * IT;

    if (t < IT) ri_s[t] = stk_ten[b * N + i0 + t];
    for (int z = t; z < IT * 132; z += 256) (&accs[0][0])[z] = 0.0f;
    __syncthreads();

    unsigned rowbase[IT];
    #pragma unroll
    for (int m = 0; m < IT; ++m) rowbase[m] = (unsigned)ri_s[m] * ST;

    const int* svb = sval + b * N;
    const int* spb = spos + b * N;
    const unsigned short* xTb = xT + (size_t)b * D * N;
    unsigned short* csw = &cs[w][0];

    f32x4 acc[8];
    #pragma unroll
    for (int nb = 0; nb < 8; ++nb)
        #pragma unroll
        for (int r = 0; r < 4; ++r) acc[nb][r] = 0.0f;

    const int jbase = w * (TPW * TJ);
    const int brow  = lane & 15;
    const int bcol  = (lane >> 4) * 8;

    // prologue: tile 0 indices + gathers
    int cj = svb[jbase + lane];
    int pj = spb[jbase + lane];
    unsigned gv[IT];
    #pragma unroll
    for (int m = 0; m < IT; ++m) gv[m] = P2[rowbase[m] + (unsigned)cj];

    for (int tt = 0; tt < TPW; ++tt) {
        const int j0  = jbase + tt * TJ;
        const int j0n = (tt == TPW - 1) ? jbase : j0 + TJ;   // clamped, discarded

        // issue next indices, then B(kc=0) — latency overlapped by coef ops
        const int cjn = svb[j0n + lane];
        const int pjn = spb[j0n + lane];
        uint4 bv[8];
        #pragma unroll
        for (int nb = 0; nb < 8; ++nb)
            bv[nb] = *(const uint4*)(xTb + (size_t)(nb * 16 + brow) * N + j0 + bcol);

        // coefficients for tile tt: select + store only
        #pragma unroll
        for (int m = 0; m < IT; ++m) {
            const bool diag = (pj == i0 + m);
            csw[m * 72 + lane] = diag ? (unsigned short)0 : (unsigned short)gv[m];
        }

        // A-fragments (same-wave LDS round-trip; lgkmcnt only, no barrier)
        const bf16x8 av0 = *(const bf16x8*)(csw + brow * 72 + bcol);
        const bf16x8 av1 = *(const bf16x8*)(csw + brow * 72 + 32 + bcol);

        // issue next tile's scattered gathers; land during MFMAs
        unsigned gvn[IT];
        #pragma unroll
        for (int m = 0; m < IT; ++m) gvn[m] = P2[rowbase[m] + (unsigned)cjn];

        #pragma unroll
        for (int nb = 0; nb < 8; ++nb)
            acc[nb] = __builtin_amdgcn_mfma_f32_16x16x32_bf16(
                av0, *(const bf16x8*)&bv[nb], acc[nb], 0, 0, 0);
        #pragma unroll
        for (int nb = 0; nb < 8; ++nb)
            bv[nb] = *(const uint4*)(xTb + (size_t)(nb * 16 + brow) * N + j0 + 32 + bcol);
        #pragma unroll
        for (int nb = 0; nb < 8; ++nb)
            acc[nb] = __builtin_amdgcn_mfma_f32_16x16x32_bf16(
                av1, *(const bf16x8*)&bv[nb], acc[nb], 0, 0, 0);

        #pragma unroll
        for (int m = 0; m < IT; ++m) gv[m] = gvn[m];
        cj = cjn; pj = pjn;
    }

    // epilogue: acc -> LDS via float atomics, reduce; l from precomputed Lb
    #pragma unroll
    for (int nb = 0; nb < 8; ++nb)
        #pragma unroll
        for (int r = 0; r < 4; ++r)
            atomicAdd(&accs[(lane >> 4) * 4 + r][nb * 16 + (lane & 15)], acc[nb][r]);
    __syncthreads();

    #pragma unroll
    for (int rr = 0; rr < 4; ++rr) {
        const int row = 4 * w + rr;
        const float linv = 1.0f / Lb[(size_t)b * ST + ri_s[row]];
        #pragma unroll
        for (int p = 0; p < 2; ++p) {
            const int dd = lane + 64 * p;
            out[((size_t)(b * N + i0 + row) << 7) + dd] = accs[row][dd] * linv;
        }
    }
}

extern "C" void kernel_launch(void* const* d_in, const int* in_sizes, int n_in,
                              void* d_out, int out_size, void* d_ws, size_t ws_size,
                              hipStream_t stream) {
    const float* x          = (const float*)d_in[0];
    const int*   stk_ten    = (const int*)d_in[1];
    const float* stk_matrix = (const float*)d_in[2];
    const float* stk_weight = (const float*)d_in[3];
    float* out = (float*)d_out;

    unsigned short* P2 = (unsigned short*)d_ws;                  // 32 MB
    int* sval = (int*)(P2 + (size_t)ST * ST);                    // 64 KB
    int* spos = sval + BATCH * N;                                // 64 KB
    unsigned short* cntT = (unsigned short*)(spos + BATCH * N);  // 64 KB
    float* Lb = (float*)(cntT + ST * 8);                         // 128 KB
    unsigned short* xT = (unsigned short*)(Lb + BATCH * ST);     // 4 MB

    sort_kernel<<<BATCH, 1024, 0, stream>>>(stk_ten, sval, spos, cntT);
    xt_kernel<<<BATCH * (N / TJ), 256, 0, stream>>>(x, spos, xT);
    pack_kernel<<<ST, 256, 0, stream>>>(stk_matrix, stk_weight, cntT, P2, Lb);
    fused_kernel<<<BATCH * (N / IT), 256, 0, stream>>>(
        xT, stk_ten, P2, sval, spos, Lb, out);
}

// Round 6
// 285.274 us; speedup vs baseline: 1.0271x; 1.0271x over previous
//
#include <hip/hip_runtime.h>
#include <hip/hip_fp16.h>
#include <math.h>

#define BATCH 8
#define N 2048
#define D 128
#define ST 4000

#define TJ 64        // j-tile per K-step
#define IT 16        // i-rows per block (one i-tile, shared by 4 k-quarter waves)
#define KQ 4         // K-quarters = waves per block
#define TPW 8        // tiles per wave = N/TJ/KQ

typedef short bf16x8 __attribute__((ext_vector_type(8)));
typedef float f32x4  __attribute__((ext_vector_type(4)));
typedef unsigned u32x4 __attribute__((ext_vector_type(4)));

__device__ __forceinline__ unsigned short f2bf(float f) {
    union { float f; unsigned u; } v; v.f = f;
    const unsigned r = v.u + 0x7FFFu + ((v.u >> 16) & 1u);   // RNE
    return (unsigned short)(r >> 16);
}

// ---------------------------------------------------------------------------
// Pack kernel: P[r][c] = (bf16(M*exp|W|) << 16) | bf16(exp|W|).
// exp precomputed here (BW-bound) so the fused coef loop is pure bit-ops.
// ---------------------------------------------------------------------------
__global__ __launch_bounds__(256) void pack_kernel(
    const float* __restrict__ M, const float* __restrict__ W,
    unsigned* __restrict__ P)
{
    const size_t i4 = ((size_t)blockIdx.x * 256 + threadIdx.x) * 4;
    const f32x4 m4 = __builtin_nontemporal_load((const f32x4*)(M + i4));
    const f32x4 w4 = __builtin_nontemporal_load((const f32x4*)(W + i4));
    u32x4 o;
    {
        const float e = __expf(fabsf(w4.x));
        o.x = ((unsigned)f2bf(m4.x * e) << 16) | (unsigned)f2bf(e);
    }
    {
        const float e = __expf(fabsf(w4.y));
        o.y = ((unsigned)f2bf(m4.y * e) << 16) | (unsigned)f2bf(e);
    }
    {
        const float e = __expf(fabsf(w4.z));
        o.z = ((unsigned)f2bf(m4.z * e) << 16) | (unsigned)f2bf(e);
    }
    {
        const float e = __expf(fabsf(w4.w));
        o.w = ((unsigned)f2bf(m4.w * e) << 16) | (unsigned)f2bf(e);
    }
    *(u32x4*)(P + i4) = o;
}

// ---------------------------------------------------------------------------
// Counting sort per batch (values < 4000). Ties in any order: the matmul is
// invariant to j-permutation.
// ---------------------------------------------------------------------------
__global__ __launch_bounds__(1024) void sort_kernel(
    const int* __restrict__ stk_ten,
    int* __restrict__ sval,
    int* __restrict__ spos)
{
    __shared__ int hist[4000];
    __shared__ int base[4000];
    __shared__ int wsum[16];
    const int b = blockIdx.x, t = threadIdx.x;
    const int lane = t & 63, wv = t >> 6;
    const int* idxb = stk_ten + b * N;

    for (int j = t; j < 4000; j += 1024) hist[j] = 0;
    __syncthreads();
    const int v0 = idxb[t], v1 = idxb[t + 1024];
    atomicAdd(&hist[v0], 1);
    atomicAdd(&hist[v1], 1);
    __syncthreads();

    // scan: thread owns bins 4t..4t+3
    int h[4], c[4], run = 0;
    #pragma unroll
    for (int i = 0; i < 4; ++i) {
        const int bi = 4 * t + i;
        h[i] = (bi < 4000) ? hist[bi] : 0;
        run += h[i];
        c[i] = run;
    }
    const int tsum = run;
    int incl = tsum;
    #pragma unroll
    for (int d = 1; d < 64; d <<= 1) {
        const int tmp = __shfl_up(incl, d, 64);
        if (lane >= d) incl += tmp;
    }
    if (lane == 63) wsum[wv] = incl;
    __syncthreads();
    if (t < 16) {
        const int v = wsum[t];
        int iv = v;
        #pragma unroll
        for (int d = 1; d < 16; d <<= 1) {
            const int tmp = __shfl_up(iv, d, 64);
            if (lane >= d) iv += tmp;
        }
        wsum[t] = iv - v;               // exclusive across waves
    }
    __syncthreads();
    const int ex = incl - tsum + wsum[wv];
    #pragma unroll
    for (int i = 0; i < 4; ++i) {
        const int bi = 4 * t + i;
        if (bi < 4000) base[bi] = ex + c[i] - h[i];
    }
    __syncthreads();
    for (int j = t; j < 4000; j += 1024) hist[j] = 0;
    __syncthreads();
    {
        const int p0 = base[v0] + atomicAdd(&hist[v0], 1);
        sval[b * N + p0] = v0; spos[b * N + p0] = t;
        const int p1 = base[v1] + atomicAdd(&hist[v1], 1);
        sval[b * N + p1] = v1; spos[b * N + p1] = t + 1024;
    }
}

// ---------------------------------------------------------------------------
// xT[b][d][j_sorted] = bf16(x[b][spos[j]][d]).  4 MB, L2-resident B operand.
// ---------------------------------------------------------------------------
__global__ __launch_bounds__(256) void xt_kernel(
    const float* __restrict__ x,
    const int* __restrict__ spos,
    unsigned short* __restrict__ xT)
{
    __shared__ float xs[TJ][129];
    __shared__ int sp_s[TJ];
    const int t  = threadIdx.x;
    const int b  = blockIdx.x >> 5;
    const int jt = blockIdx.x & 31;
    const int j0 = jt * TJ;
    if (t < TJ) sp_s[t] = spos[b * N + j0 + t];
    __syncthreads();
    const int tx = t & 31, ty = t >> 5;
    const float* xb = x + (size_t)b * N * D;
    #pragma unroll
    for (int p = 0; p < 8; ++p) {
        const int r = ty + 8 * p;
        const float* src = xb + (size_t)sp_s[r] * D;
        #pragma unroll
        for (int i = 0; i < 4; ++i)
            xs[r][tx + 32 * i] = src[tx + 32 * i];
    }
    __syncthreads();
    const int jp = t & 31, dd0 = t >> 5;
    unsigned short* xTb = xT + (size_t)b * D * N;
    #pragma unroll
    for (int q = 0; q < 16; ++q) {
        const int dd = dd0 + 8 * q;
        const unsigned lo = f2bf(xs[2 * jp][dd]);
        const unsigned hi = f2bf(xs[2 * jp + 1][dd]);
        *(unsigned*)(xTb + (size_t)dd * N + j0 + 2 * jp) = (hi << 16) | lo;
    }
}

// ---------------------------------------------------------------------------
// Fused kernel, round 6: register-free gathers via global_load_lds.
// Established (r0-r5): duration tracks gather MLP; register-destined gathers
// serialize whenever the allocator lands <=64 VGPR, and every occupancy
// attribute forces that. Also: bv loads issued AFTER the next-tile gathers
// force the MFMA's compiler waitcnt to drain the prefetch (vmcnt retires
// oldest-first; waiting on the NEWEST load = vmcnt(0)).
// Fix: gathers go straight to LDS (pg, double-buffered; dest = base+lane*4
// matches [m][lane]); issue order per tile: bv[16] first, THEN glds[16],
// then manual s_waitcnt vmcnt(32) (retires exactly the 16 oldest = previous
// tile's gathers; over-waits only). MFMA's auto-wait for bv then leaves the
// next tile's gathers in flight across the whole MFMA phase.
// Coef loop reads pg from LDS (lane-consecutive, conflict-free).
// No occupancy attribute. LDS ~50.8KB -> 3 blocks/CU.
// ---------------------------------------------------------------------------
__global__ __launch_bounds__(256) void fused_kernel(
    const unsigned short* __restrict__ xT,
    const int* __restrict__ stk_ten,
    const unsigned* __restrict__ P,
    const int* __restrict__ sval,
    const int* __restrict__ spos,
    float* __restrict__ out)
{
    __shared__ __align__(16) unsigned short cs[KQ][IT * 72]; // 9216 B
    __shared__ __align__(16) unsigned pg[KQ][2][IT * 64];    // 32768 B
    __shared__ float accs[IT][132];                          // 8448 B
    __shared__ float lbuf[KQ][IT];
    __shared__ int ri_s[IT];

    const int t    = threadIdx.x;
    const int lane = t & 63;
    const int w    = t >> 6;
    const int wg   = (blockIdx.x & 7) * 128 + (blockIdx.x >> 3);  // batch->XCD
    const int b    = wg >> 7;                    // 128 i-tiles per batch
    const int i0   = (wg & 127) * IT;

    if (t < IT) ri_s[t] = stk_ten[b * N + i0 + t];
    for (int z = t; z < IT * 132; z += 256) (&accs[0][0])[z] = 0.0f;
    __syncthreads();

    unsigned rowoff[IT];
    #pragma unroll
    for (int m = 0; m < IT; ++m) rowoff[m] = (unsigned)ri_s[m] * ST;

    const int* svb = sval + b * N;
    const int* spb = spos + b * N;
    const unsigned short* xTb = xT + (size_t)b * D * N;
    unsigned short* csw = &cs[w][0];
    unsigned* pgw = &pg[w][0][0];

    f32x4 acc[8];
    #pragma unroll
    for (int nb = 0; nb < 8; ++nb)
        #pragma unroll
        for (int r = 0; r < 4; ++r) acc[nb][r] = 0.0f;
    float l_part[IT];
    #pragma unroll
    for (int m = 0; m < IT; ++m) l_part[m] = 0.0f;

    const int jbase = w * (TPW * TJ);
    const int brow  = lane & 15;
    const int bcol  = (lane >> 4) * 8;

    // prologue: tile 0/1 indices; tile-0 gathers straight to LDS buf 0
    int pj  = spb[jbase + lane];
    int cjn = svb[jbase + TJ + lane];
    int pjn = spb[jbase + TJ + lane];
    {
        const int cj0 = svb[jbase + lane];
        #pragma unroll
        for (int m = 0; m < IT; ++m)
            __builtin_amdgcn_global_load_lds(
                (const unsigned*)(P + rowoff[m] + (unsigned)cj0),
                pgw + m * 64, 4, 0, 0);
    }

    int buf = 0;
    for (int tt = 0; tt < TPW; ++tt) {
        const int j0 = jbase + tt * TJ;
        const int j2 = (tt + 2 < TPW) ? j0 + 2 * TJ : jbase;  // wrap: discarded

        // 1) ALL bv loads for tile tt first (oldest-first waitcnt discipline)
        uint4 bv0[8], bv1[8];
        #pragma unroll
        for (int nb = 0; nb < 8; ++nb)
            bv0[nb] = *(const uint4*)(xTb + (size_t)(nb * 16 + brow) * N + j0 + bcol);
        #pragma unroll
        for (int nb = 0; nb < 8; ++nb)
            bv1[nb] = *(const uint4*)(xTb + (size_t)(nb * 16 + brow) * N + j0 + 32 + bcol);

        // 2) next tile's gathers -> LDS buf^1 (no dest registers)
        unsigned* pgn = pgw + (buf ^ 1) * (IT * 64);
        #pragma unroll
        for (int m = 0; m < IT; ++m)
            __builtin_amdgcn_global_load_lds(
                (const unsigned*)(P + rowoff[m] + (unsigned)cjn),
                pgn + m * 64, 4, 0, 0);

        // 3) retire the 16 oldest in-flight ops = tile tt's gathers
        asm volatile("s_waitcnt vmcnt(32)" ::: "memory");
        __builtin_amdgcn_sched_barrier(0);

        // 2-deep index prefetch (after the wait so it doesn't inflate counts)
        const int cj2 = svb[j2 + lane];
        const int pj2 = spb[j2 + lane];

        // 4) coefficients for tile tt from LDS: hi=bf16(m*e), lo=bf16(e)
        const unsigned* pgr = pgw + buf * (IT * 64);
        #pragma unroll
        for (int m = 0; m < IT; ++m) {
            const unsigned u = pgr[m * 64 + lane];
            const bool diag = (pj == i0 + m);
            l_part[m] += diag ? 1.0f : __uint_as_float(u << 16);
            csw[m * 72 + lane] = diag ? (unsigned short)0 : (unsigned short)(u >> 16);
        }

        // A-fragments (same-wave LDS round-trip; lgkmcnt only, no barrier)
        const bf16x8 av0 = *(const bf16x8*)(csw + brow * 72 + bcol);
        const bf16x8 av1 = *(const bf16x8*)(csw + brow * 72 + 32 + bcol);

        // 5) MFMAs: bv waits leave the tt+1 gathers in flight
        #pragma unroll
        for (int nb = 0; nb < 8; ++nb)
            acc[nb] = __builtin_amdgcn_mfma_f32_16x16x32_bf16(
                av0, *(const bf16x8*)&bv0[nb], acc[nb], 0, 0, 0);
        #pragma unroll
        for (int nb = 0; nb < 8; ++nb)
            acc[nb] = __builtin_amdgcn_mfma_f32_16x16x32_bf16(
                av1, *(const bf16x8*)&bv1[nb], acc[nb], 0, 0, 0);

        buf ^= 1; pj = pjn; cjn = cj2; pjn = pj2;
    }

    // epilogue: l butterfly (once), acc -> LDS via float atomics, reduce
    #pragma unroll
    for (int m = 0; m < IT; ++m) {
        float v = l_part[m];
        #pragma unroll
        for (int d = 1; d < 64; d <<= 1) v += __shfl_xor(v, d, 64);
        if (lane == 0) lbuf[w][m] = v;
    }
    #pragma unroll
    for (int nb = 0; nb < 8; ++nb)
        #pragma unroll
        for (int r = 0; r < 4; ++r)
            atomicAdd(&accs[(lane >> 4) * 4 + r][nb * 16 + (lane & 15)], acc[nb][r]);
    __syncthreads();

    #pragma unroll
    for (int rr = 0; rr < 4; ++rr) {
        const int row = 4 * w + rr;
        const float linv = 1.0f /
            (lbuf[0][row] + lbuf[1][row] + lbuf[2][row] + lbuf[3][row]);
        #pragma unroll
        for (int p = 0; p < 2; ++p) {
            const int dd = lane + 64 * p;
            out[((size_t)(b * N + i0 + row) << 7) + dd] = accs[row][dd] * linv;
        }
    }
}

extern "C" void kernel_launch(void* const* d_in, const int* in_sizes, int n_in,
                              void* d_out, int out_size, void* d_ws, size_t ws_size,
                              hipStream_t stream) {
    const float* x          = (const float*)d_in[0];
    const int*   stk_ten    = (const int*)d_in[1];
    const float* stk_matrix = (const float*)d_in[2];
    const float* stk_weight = (const float*)d_in[3];
    float* out = (float*)d_out;

    unsigned* P = (unsigned*)d_ws;                              // 64 MB
    int* sval = (int*)(P + (size_t)ST * ST);                    // 64 KB
    int* spos = sval + BATCH * N;                               // 64 KB
    unsigned short* xT = (unsigned short*)(spos + BATCH * N);   // 4 MB

    pack_kernel<<<(ST * ST) / 1024, 256, 0, stream>>>(stk_matrix, stk_weight, P);
    sort_kernel<<<BATCH, 1024, 0, stream>>>(stk_ten, sval, spos);
    xt_kernel<<<BATCH * (N / TJ), 256, 0, stream>>>(x, spos, xT);
    fused_kernel<<<BATCH * (N / IT), 256, 0, stream>>>(
        xT, stk_ten, P, sval, spos, out);
}